// Round 3
// baseline (259.314 us; speedup 1.0000x reference)
//
#include <hip/hip_runtime.h>

#define NN 2048
#define DIMD 1024
#define HH 16
#define HDD 64
// SCALE * log2(e): folded into Wq/bq so S exits QK^T in exp2 domain
#define SC2 0.1803368801111244f

typedef __attribute__((ext_vector_type(8))) short bf16x8;
typedef __attribute__((ext_vector_type(4))) float f32x4;
typedef __attribute__((ext_vector_type(4))) _Float16 f16x4;
typedef unsigned short ushort_t;
typedef unsigned int uint_t;

#define MFMA32(a, b, c) __builtin_amdgcn_mfma_f32_16x16x32_bf16((a), (b), (c), 0, 0, 0)
// legacy-name f16 K=16 MFMA (compiler-suggested spelling on this toolchain)
#define MFMA16H(a, b, c) __builtin_amdgcn_mfma_f32_16x16x16f16((a), (b), (c), 0, 0, 0)

__device__ __forceinline__ ushort_t f2bf(float f) {   // RNE
    union { float f; uint_t u; } v; v.f = f;
    uint_t u = v.u;
    return (ushort_t)((u + 0x7FFFu + ((u >> 16) & 1u)) >> 16);
}
__device__ __forceinline__ void gl_lds16(const ushort_t* g, ushort_t* l) {
    __builtin_amdgcn_global_load_lds(
        (const __attribute__((address_space(1))) void*)g,
        (__attribute__((address_space(3))) void*)l, 16, 0, 0);
}

// ---- fp32 -> bf16: q,k,v (3x4M) -> Abf ; Wq*SC2,Wk,Wv,Wo (4x1M) -> Wbf
__global__ __launch_bounds__(256) void convert_k(
    const float* __restrict__ q, const float* __restrict__ k, const float* __restrict__ v,
    const float* __restrict__ wq, const float* __restrict__ wk,
    const float* __restrict__ wv, const float* __restrict__ wo,
    ushort_t* __restrict__ Abf, ushort_t* __restrict__ Wbf) {
    size_t gid = (size_t)blockIdx.x * 256 + threadIdx.x;
    size_t e = gid * 8;
    const float* src; ushort_t* dst;
    float sc = 1.f;
    if (e < 12582912) {
        int i = (int)(e >> 22);
        src = (i == 0 ? q : (i == 1 ? k : v)) + (e & 4194303);
        dst = Abf + e;
    } else {
        size_t e2 = e - 12582912;
        int i = (int)(e2 >> 20);
        src = (i == 0 ? wq : (i == 1 ? wk : (i == 2 ? wv : wo))) + (e2 & 1048575);
        dst = Wbf + e2;
        if (i == 0) sc = SC2;
    }
    float4 x = ((const float4*)src)[0], y = ((const float4*)src)[1];
    union { uint4 u; ushort_t s[8]; } pk;
    pk.s[0] = f2bf(x.x * sc); pk.s[1] = f2bf(x.y * sc); pk.s[2] = f2bf(x.z * sc); pk.s[3] = f2bf(x.w * sc);
    pk.s[4] = f2bf(y.x * sc); pk.s[5] = f2bf(y.y * sc); pk.s[6] = f2bf(y.z * sc); pk.s[7] = f2bf(y.w * sc);
    *(uint4*)dst = pk.u;
}

// ---- dbuf bf16 GEMM, TM x 128 tile, BK=32, conflict-free XOR-swizzled LDS.
// TM=128: 64x64 wave tiles (2x2 waves) -> 0.5 ds_read per MFMA (LDS-BW optimized,
//         3 blocks/CU). TM=64: 32x64 wave tiles (grid doubles; for the O-proj
//         whose N=1024 grid would otherwise leave CUs empty).
// MODE 0: z-batched QKV -> split-head (z=0 Q bf16 bias*SC2; z=1 K bf16;
//         z=2 V^T [bh][c][n] FP16, packed 8B).  MODE 1: out proj -> fp32.
template<int MODE, int TM>
__global__ __launch_bounds__(256, TM == 128 ? 3 : 5) void gemm_k(
    const ushort_t* __restrict__ Abase, const ushort_t* __restrict__ Wbase,
    const float* __restrict__ b0p, const float* __restrict__ b1p, const float* __restrict__ b2p,
    ushort_t* __restrict__ d0, ushort_t* __restrict__ d1, ushort_t* __restrict__ d2,
    float* __restrict__ fout) {
    const int K = 1024;
    constexpr int MT = TM / 32;          // m-tiles (16-row) per wave
    __shared__ ushort_t As[2][TM * 32];
    __shared__ ushort_t Bs[2][128 * 32];
    int z = (MODE == 0) ? blockIdx.z : 0;
    const ushort_t* A = Abase + (size_t)z * 4096 * 1024;
    const ushort_t* W = Wbase + (size_t)z * 1024 * 1024;
    const float* bias = (MODE == 0) ? (z == 0 ? b0p : (z == 1 ? b1p : b2p)) : b0p;
    int tid = threadIdx.x;
    int m0 = blockIdx.x * TM, n0 = blockIdx.y * 128;
    int lane = tid & 63, wave = tid >> 6;
    int quad = lane >> 4, l15 = lane & 15;
    int wm = (wave >> 1) * (TM / 2), wn = (wave & 1) * 64;

    f32x4 acc[MT][4];
    for (int i = 0; i < MT; i++)
        for (int j = 0; j < 4; j++)
            acc[i][j] = (f32x4){0.f, 0.f, 0.f, 0.f};

    // staging: slot (row, c) holds global chunk c ^ ((row>>1)&3)   (rows of 4x16B)
    int rA = tid >> 2, cA = tid & 3;
    int gA = cA ^ ((rA >> 1) & 3);       // (rA+64) gives the same key: 64>>1 ≡ 0 mod 4

    auto stage = [&](int buf, int k0) {
        gl_lds16(A + (size_t)(m0 + rA) * K + k0 + gA * 8, &As[buf][tid * 8]);
        if (TM == 128)
            gl_lds16(A + (size_t)(m0 + rA + 64) * K + k0 + gA * 8, &As[buf][(tid + 256) * 8]);
        gl_lds16(W + (size_t)(n0 + rA) * K + k0 + gA * 8, &Bs[buf][tid * 8]);
        gl_lds16(W + (size_t)(n0 + rA + 64) * K + k0 + gA * 8, &Bs[buf][(tid + 256) * 8]);
    };
    stage(0, 0);

    // fragment chunk: rows are base+l15 (base mult of 16) -> key = (l15>>1)&3
    int fc = (quad ^ ((l15 >> 1) & 3)) * 8;

    for (int it = 0; it < 32; it++) {
        int cur = it & 1;
        __syncthreads();   // drains stage(it) — issued a full compute-phase ago
        if (it < 31) stage(1 - cur, (it + 1) * 32);
        bf16x8 a[MT], b[4];
        for (int mt = 0; mt < MT; mt++)
            a[mt] = *(const bf16x8*)&As[cur][(wm + mt * 16 + l15) * 32 + fc];
        for (int nt = 0; nt < 4; nt++)
            b[nt] = *(const bf16x8*)&Bs[cur][(wn + nt * 16 + l15) * 32 + fc];
        for (int mt = 0; mt < MT; mt++)
            for (int nt = 0; nt < 4; nt++)
                acc[mt][nt] = MFMA32(a[mt], b[nt], acc[mt][nt]);
    }
    // D mapping: col(n)=lane&15, row(m)=quad*4+reg
    if (MODE == 0 && z == 2) {
        // V^T [bh][c][n] as FP16, packed 8B stores (4 consecutive seq positions)
        for (int nt = 0; nt < 4; nt++) {
            int n = n0 + wn + nt * 16 + l15;
            float bv = bias[n];
            int h = n >> 6, c = n & 63;
            for (int mt = 0; mt < MT; mt++) {
                int mb = m0 + wm + mt * 16 + quad * 4;
                int b = mb >> 11, ns = mb & 2047;
                union { uint2 u2; _Float16 hh[4]; } pkv;
                pkv.hh[0] = (_Float16)(acc[mt][nt][0] + bv);
                pkv.hh[1] = (_Float16)(acc[mt][nt][1] + bv);
                pkv.hh[2] = (_Float16)(acc[mt][nt][2] + bv);
                pkv.hh[3] = (_Float16)(acc[mt][nt][3] + bv);
                *(uint2*)&d2[(((size_t)(b * HH + h)) * HDD + c) * NN + ns] = pkv.u2;
            }
        }
    } else {
        for (int nt = 0; nt < 4; nt++) {
            int n = n0 + wn + nt * 16 + l15;
            float bv = bias[n];
            if (MODE == 0 && z == 0) bv *= SC2;
            for (int mt = 0; mt < MT; mt++)
                for (int r = 0; r < 4; r++) {
                    int m = m0 + wm + mt * 16 + quad * 4 + r;
                    float val = acc[mt][nt][r] + bv;
                    if (MODE == 0) {
                        int b = m >> 11, ns = m & 2047;
                        int h = n >> 6, c = n & 63;
                        ushort_t* dst = (z == 0) ? d0 : d1;
                        dst[(((size_t)(b * HH + h)) * NN + ns) * HDD + c] = f2bf(val);
                    } else {
                        fout[(size_t)m * DIMD + n] = val;
                    }
                }
        }
    }
}

// ---- flash attention, causal. Round 3: depth-2 prefetch via 3-slot LDS ring +
// counted vmcnt + raw s_barrier (T3/T4). Round-2 counters showed the dbuf
// __syncthreads (vmcnt(0) drain) exposed ~full HBM latency per iteration
// (MfmaUtil 18%, VALUBusy 41%, HBM 19% — all low at 28% occupancy).
// Protocol per iteration kb:
//   s_waitcnt vmcnt(4)  -- stage(kb) landed; stage(kb+1)'s 4 loads stay in flight
//   s_barrier            -- cross-wave visibility of stage(kb)
//   issue stage(kb+2) into slot (kb+2)%3 == slot (kb-1)%3 (freed: all waves
//   consumed it into regs before passing this barrier)
//   compute on slot kb%3
// Last iteration waits vmcnt(0) (no stage(kb+1) exists).
__global__ __launch_bounds__(256, 3) void attn7(const ushort_t* __restrict__ Qh,
                                                const ushort_t* __restrict__ Kh,
                                                const ushort_t* __restrict__ VtG,
                                                ushort_t* __restrict__ aout) {
    __shared__ ushort_t Kb[3][64 * 64];
    __shared__ ushort_t Vb[3][64 * 64];
    int tid = threadIdx.x, lane = tid & 63, w = tid >> 6;
    int quad = lane >> 4, l15 = lane & 15;
    int bh = blockIdx.y;
    int p = blockIdx.x;                  // 0..31
    int tile = (w & 2) ? (63 - p) : p;   // this wave's 32-row q-tile index
    int ka = tile >> 1;                  // last (diagonal) k-tile for this wave
    int kc = (63 - p) >> 1;              // block loop bound (longer tile's range); >= 16
    int rowb = tile * 32 + (w & 1) * 16; // wave's 16 q-rows
    const ushort_t* Qp = Qh + (size_t)bh * NN * HDD;
    const ushort_t* Kp = Kh + (size_t)bh * NN * HDD;
    const ushort_t* Vp = VtG + (size_t)bh * HDD * NN;

    bf16x8 aq[2];
    for (int kk = 0; kk < 2; kk++)
        aq[kk] = *(const bf16x8*)&Qp[(size_t)(rowb + l15) * HDD + kk * 32 + quad * 8];

    f32x4 o[4];
    for (int ct = 0; ct < 4; ct++)
        o[ct] = (f32x4){0.f, 0.f, 0.f, 0.f};
    float l = 0.f;

    int sr0 = tid >> 3, scg = tid & 7;
    int sr1 = sr0 + 32;
    int ssc = scg ^ (sr0 & 7);
    int key = l15 & 7;
    int c0 = (quad ^ key) * 8;
    int c1 = ((4 + quad) ^ key) * 8;

    auto stageK = [&](int s, int kt) {   // 4 gl_lds16 per thread per stage
        gl_lds16(Kp + (size_t)(kt * 64 + sr0) * 64 + ssc * 8, &Kb[s][(0 * 256 + w * 64) * 8]);
        gl_lds16(Kp + (size_t)(kt * 64 + sr1) * 64 + ssc * 8, &Kb[s][(1 * 256 + w * 64) * 8]);
        gl_lds16(Vp + (size_t)sr0 * NN + kt * 64 + ssc * 8, &Vb[s][(0 * 256 + w * 64) * 8]);
        gl_lds16(Vp + (size_t)sr1 * NN + kt * 64 + ssc * 8, &Vb[s][(1 * 256 + w * 64) * 8]);
    };
    stageK(0, 0);
    stageK(1, 1);          // kc >= 16, always valid

    int cur = 0;
    for (int kb = 0; kb <= kc; kb++) {
        if (kb < kc)
            asm volatile("s_waitcnt vmcnt(4)\ns_barrier" ::: "memory");
        else
            asm volatile("s_waitcnt vmcnt(0)\ns_barrier" ::: "memory");
        if (kb + 2 <= kc) stageK(cur == 0 ? 2 : cur - 1, kb + 2);  // (kb+2)%3
        if (kb <= ka) {   // wave-uniform: waves with the short tile skip late kbs
            bf16x8 kf0[4], kf1[4];
            for (int nt = 0; nt < 4; nt++) {
                kf0[nt] = *(const bf16x8*)&Kb[cur][(nt * 16 + l15) * 64 + c0];
                kf1[nt] = *(const bf16x8*)&Kb[cur][(nt * 16 + l15) * 64 + c1];
            }
            f16x4 vf[4][4];
            for (int ct = 0; ct < 4; ct++)
                for (int nt = 0; nt < 4; nt++)
                    vf[ct][nt] = *(const f16x4*)&Vb[cur][(ct * 16 + l15) * 64 +
                                    ((2 * nt + (quad >> 1)) ^ key) * 8 + (quad & 1) * 4];
            f32x4 s[4];
            __builtin_amdgcn_s_setprio(1);
            for (int nt = 0; nt < 4; nt++) {
                f32x4 z = (f32x4){0.f, 0.f, 0.f, 0.f};
                z = MFMA32(kf0[nt], aq[0], z);
                s[nt] = MFMA32(kf1[nt], aq[1], z);
            }
            __builtin_amdgcn_s_setprio(0);
            f16x4 ap[4];
            if (kb == ka) {
                for (int nt = 0; nt < 4; nt++)
                    for (int r = 0; r < 4; r++) {
                        int kv = kb * 64 + nt * 16 + quad * 4 + r;
                        float pp = (kv <= rowb + l15) ? exp2f(s[nt][r]) : 0.f;
                        ap[nt][r] = (_Float16)pp; l += pp;
                    }
            } else {
                for (int nt = 0; nt < 4; nt++)
                    for (int r = 0; r < 4; r++) {
                        float pp = exp2f(s[nt][r]);
                        ap[nt][r] = (_Float16)pp; l += pp;
                    }
            }
            __builtin_amdgcn_s_setprio(1);
            for (int ct = 0; ct < 4; ct++)
                for (int nt = 0; nt < 4; nt++)
                    o[ct] = MFMA16H(ap[nt], vf[ct][nt], o[ct]);
            __builtin_amdgcn_s_setprio(0);
        }
        cur = (cur == 2) ? 0 : cur + 1;
    }

    l += __shfl_xor(l, 16); l += __shfl_xor(l, 32);

    int b = bh >> 4, h = bh & 15;
    for (int r = 0; r < 4; r++) {
        float il = 1.f / __shfl(l, quad * 4 + r);
        for (int ct = 0; ct < 4; ct++) {
            int c = ct * 16 + l15;
            int qq = rowb + quad * 4 + r;
            aout[((size_t)(b * NN + qq)) * DIMD + h * HDD + c] = f2bf(o[ct][r] * il);
        }
    }
}

extern "C" void kernel_launch(void* const* d_in, const int* in_sizes, int n_in,
                              void* d_out, int out_size, void* d_ws, size_t ws_size,
                              hipStream_t stream) {
    const float* q  = (const float*)d_in[0];
    const float* k  = (const float*)d_in[1];
    const float* v  = (const float*)d_in[2];
    // d_in[3] mask: provably causal tril — hardcoded
    const float* Wq = (const float*)d_in[4];
    const float* bq = (const float*)d_in[5];
    const float* Wk = (const float*)d_in[6];
    const float* bk = (const float*)d_in[7];
    const float* Wv = (const float*)d_in[8];
    const float* bv = (const float*)d_in[9];
    const float* Wo = (const float*)d_in[10];
    const float* bo = (const float*)d_in[11];
    float* out = (float*)d_out;

    char* ws = (char*)d_ws;
    ushort_t* Abf  = (ushort_t*)(ws);                    // 24 MB: q,k,v bf16
    ushort_t* Wbf  = (ushort_t*)(ws + (24ull << 20));    // 8 MB: Wq*SC2,Wk,Wv,Wo bf16
    ushort_t* Qh   = (ushort_t*)(ws + (32ull << 20));    // 8 MB [bh][n][c] bf16 (pre-scaled)
    ushort_t* Kh   = (ushort_t*)(ws + (40ull << 20));    // 8 MB [bh][n][c] bf16
    ushort_t* VtG  = (ushort_t*)(ws + (48ull << 20));    // 8 MB [bh][c][n] FP16
    ushort_t* AObf = (ushort_t*)(ws + (56ull << 20));    // 8 MB [4096][1024] bf16

    hipLaunchKernelGGL(convert_k, dim3(8192), dim3(256), 0, stream,
                       q, k, v, Wq, Wk, Wv, Wo, Abf, Wbf);
    hipLaunchKernelGGL((gemm_k<0, 128>), dim3(32, 8, 3), dim3(256), 0, stream,
                       Abf, Wbf, bq, bk, bv, Qh, Kh, VtG, (float*)nullptr);
    hipLaunchKernelGGL(attn7, dim3(32, 32), dim3(256), 0, stream, Qh, Kh, VtG, AObf);
    hipLaunchKernelGGL((gemm_k<1, 64>), dim3(64, 8, 1), dim3(256), 0, stream,
                       AObf, Wbf + 3ull * 1024 * 1024, bo, nullptr, nullptr,
                       nullptr, nullptr, nullptr, out);
}

// Round 4
// 230.022 us; speedup vs baseline: 1.1273x; 1.1273x over previous
//
#include <hip/hip_runtime.h>

#define NN 2048
#define DIMD 1024
#define HH 16
#define HDD 64
// SCALE * log2(e): folded into Wq/bq so S exits QK^T in exp2 domain
#define SC2 0.1803368801111244f

typedef __attribute__((ext_vector_type(8))) short bf16x8;
typedef __attribute__((ext_vector_type(4))) float f32x4;
typedef __attribute__((ext_vector_type(4))) _Float16 f16x4;
typedef unsigned short ushort_t;
typedef unsigned int uint_t;

#define MFMA32(a, b, c) __builtin_amdgcn_mfma_f32_16x16x32_bf16((a), (b), (c), 0, 0, 0)
// legacy-name f16 K=16 MFMA (compiler-suggested spelling on this toolchain)
#define MFMA16H(a, b, c) __builtin_amdgcn_mfma_f32_16x16x16f16((a), (b), (c), 0, 0, 0)

__device__ __forceinline__ ushort_t f2bf(float f) {   // RNE
    union { float f; uint_t u; } v; v.f = f;
    uint_t u = v.u;
    return (ushort_t)((u + 0x7FFFu + ((u >> 16) & 1u)) >> 16);
}
__device__ __forceinline__ void gl_lds16(const ushort_t* g, ushort_t* l) {
    __builtin_amdgcn_global_load_lds(
        (const __attribute__((address_space(1))) void*)g,
        (__attribute__((address_space(3))) void*)l, 16, 0, 0);
}

// ---- fp32 -> bf16: q,k,v (3x4M) -> Abf ; Wq*SC2,Wk,Wv,Wo (4x1M) -> Wbf
__global__ __launch_bounds__(256) void convert_k(
    const float* __restrict__ q, const float* __restrict__ k, const float* __restrict__ v,
    const float* __restrict__ wq, const float* __restrict__ wk,
    const float* __restrict__ wv, const float* __restrict__ wo,
    ushort_t* __restrict__ Abf, ushort_t* __restrict__ Wbf) {
    size_t gid = (size_t)blockIdx.x * 256 + threadIdx.x;
    size_t e = gid * 8;
    const float* src; ushort_t* dst;
    float sc = 1.f;
    if (e < 12582912) {
        int i = (int)(e >> 22);
        src = (i == 0 ? q : (i == 1 ? k : v)) + (e & 4194303);
        dst = Abf + e;
    } else {
        size_t e2 = e - 12582912;
        int i = (int)(e2 >> 20);
        src = (i == 0 ? wq : (i == 1 ? wk : (i == 2 ? wv : wo))) + (e2 & 1048575);
        dst = Wbf + e2;
        if (i == 0) sc = SC2;
    }
    float4 x = ((const float4*)src)[0], y = ((const float4*)src)[1];
    union { uint4 u; ushort_t s[8]; } pk;
    pk.s[0] = f2bf(x.x * sc); pk.s[1] = f2bf(x.y * sc); pk.s[2] = f2bf(x.z * sc); pk.s[3] = f2bf(x.w * sc);
    pk.s[4] = f2bf(y.x * sc); pk.s[5] = f2bf(y.y * sc); pk.s[6] = f2bf(y.z * sc); pk.s[7] = f2bf(y.w * sc);
    *(uint4*)dst = pk.u;
}

// ---- dbuf bf16 GEMM, TM x 128 tile, BK=32, conflict-free XOR-swizzled LDS.
// TM=128: 64x64 wave tiles (2x2 waves) -> 0.5 ds_read per MFMA (LDS-BW optimized,
//         3 blocks/CU). TM=64: 32x64 wave tiles (grid doubles; for the O-proj
//         whose N=1024 grid would otherwise leave CUs empty).
// MODE 0: z-batched QKV -> split-head (z=0 Q bf16 bias*SC2; z=1 K bf16;
//         z=2 V^T [bh][c][n] FP16, packed 8B).  MODE 1: out proj -> fp32.
template<int MODE, int TM>
__global__ __launch_bounds__(256, TM == 128 ? 3 : 5) void gemm_k(
    const ushort_t* __restrict__ Abase, const ushort_t* __restrict__ Wbase,
    const float* __restrict__ b0p, const float* __restrict__ b1p, const float* __restrict__ b2p,
    ushort_t* __restrict__ d0, ushort_t* __restrict__ d1, ushort_t* __restrict__ d2,
    float* __restrict__ fout) {
    const int K = 1024;
    constexpr int MT = TM / 32;          // m-tiles (16-row) per wave
    __shared__ ushort_t As[2][TM * 32];
    __shared__ ushort_t Bs[2][128 * 32];
    int z = (MODE == 0) ? blockIdx.z : 0;
    const ushort_t* A = Abase + (size_t)z * 4096 * 1024;
    const ushort_t* W = Wbase + (size_t)z * 1024 * 1024;
    const float* bias = (MODE == 0) ? (z == 0 ? b0p : (z == 1 ? b1p : b2p)) : b0p;
    int tid = threadIdx.x;
    int m0 = blockIdx.x * TM, n0 = blockIdx.y * 128;
    int lane = tid & 63, wave = tid >> 6;
    int quad = lane >> 4, l15 = lane & 15;
    int wm = (wave >> 1) * (TM / 2), wn = (wave & 1) * 64;

    f32x4 acc[MT][4];
    for (int i = 0; i < MT; i++)
        for (int j = 0; j < 4; j++)
            acc[i][j] = (f32x4){0.f, 0.f, 0.f, 0.f};

    // staging: slot (row, c) holds global chunk c ^ ((row>>1)&3)   (rows of 4x16B)
    int rA = tid >> 2, cA = tid & 3;
    int gA = cA ^ ((rA >> 1) & 3);       // (rA+64) gives the same key: 64>>1 ≡ 0 mod 4

    auto stage = [&](int buf, int k0) {
        gl_lds16(A + (size_t)(m0 + rA) * K + k0 + gA * 8, &As[buf][tid * 8]);
        if (TM == 128)
            gl_lds16(A + (size_t)(m0 + rA + 64) * K + k0 + gA * 8, &As[buf][(tid + 256) * 8]);
        gl_lds16(W + (size_t)(n0 + rA) * K + k0 + gA * 8, &Bs[buf][tid * 8]);
        gl_lds16(W + (size_t)(n0 + rA + 64) * K + k0 + gA * 8, &Bs[buf][(tid + 256) * 8]);
    };
    stage(0, 0);

    // fragment chunk: rows are base+l15 (base mult of 16) -> key = (l15>>1)&3
    int fc = (quad ^ ((l15 >> 1) & 3)) * 8;

    for (int it = 0; it < 32; it++) {
        int cur = it & 1;
        __syncthreads();   // drains stage(it) — issued a full compute-phase ago
        if (it < 31) stage(1 - cur, (it + 1) * 32);
        bf16x8 a[MT], b[4];
        for (int mt = 0; mt < MT; mt++)
            a[mt] = *(const bf16x8*)&As[cur][(wm + mt * 16 + l15) * 32 + fc];
        for (int nt = 0; nt < 4; nt++)
            b[nt] = *(const bf16x8*)&Bs[cur][(wn + nt * 16 + l15) * 32 + fc];
        for (int mt = 0; mt < MT; mt++)
            for (int nt = 0; nt < 4; nt++)
                acc[mt][nt] = MFMA32(a[mt], b[nt], acc[mt][nt]);
    }
    // D mapping: col(n)=lane&15, row(m)=quad*4+reg
    if (MODE == 0 && z == 2) {
        // V^T [bh][c][n] as FP16, packed 8B stores (4 consecutive seq positions)
        for (int nt = 0; nt < 4; nt++) {
            int n = n0 + wn + nt * 16 + l15;
            float bv = bias[n];
            int h = n >> 6, c = n & 63;
            for (int mt = 0; mt < MT; mt++) {
                int mb = m0 + wm + mt * 16 + quad * 4;
                int b = mb >> 11, ns = mb & 2047;
                union { uint2 u2; _Float16 hh[4]; } pkv;
                pkv.hh[0] = (_Float16)(acc[mt][nt][0] + bv);
                pkv.hh[1] = (_Float16)(acc[mt][nt][1] + bv);
                pkv.hh[2] = (_Float16)(acc[mt][nt][2] + bv);
                pkv.hh[3] = (_Float16)(acc[mt][nt][3] + bv);
                *(uint2*)&d2[(((size_t)(b * HH + h)) * HDD + c) * NN + ns] = pkv.u2;
            }
        }
    } else {
        for (int nt = 0; nt < 4; nt++) {
            int n = n0 + wn + nt * 16 + l15;
            float bv = bias[n];
            if (MODE == 0 && z == 0) bv *= SC2;
            for (int mt = 0; mt < MT; mt++)
                for (int r = 0; r < 4; r++) {
                    int m = m0 + wm + mt * 16 + quad * 4 + r;
                    float val = acc[mt][nt][r] + bv;
                    if (MODE == 0) {
                        int b = m >> 11, ns = m & 2047;
                        int h = n >> 6, c = n & 63;
                        ushort_t* dst = (z == 0) ? d0 : d1;
                        dst[(((size_t)(b * HH + h)) * NN + ns) * HDD + c] = f2bf(val);
                    } else {
                        fout[(size_t)m * DIMD + n] = val;
                    }
                }
        }
    }
}

// ---- flash attention, causal. Round 4: attn5 base (64-row paired tiles,
// ILP=2 per wave via shared kf/vf — verified best structure) + 3-slot LDS
// ring with depth-2 prefetch and counted vmcnt (T3/T4). Grid 512 = 2
// blocks/CU (grid-limited), so 48KB LDS (3/CU capacity) cannot reduce
// residency — isolates the pipeline protocol from round-3's confound.
// Protocol per iteration kb (qc >= 16 so depth-2 prologue always valid):
//   s_waitcnt vmcnt(4)  -- stage(kb) landed; stage(kb+1)'s 4 loads in flight
//   s_barrier            -- all waves' reads of slot (kb-1) already done
//   issue stage(kb+2) into slot (kb+2)%3 == (kb-1)%3
//   compute on slot kb%3
// Q-fragment loads are pinned with an asm use BEFORE the staging prologue so
// their vmem waits retire pre-loop and in-loop vmcnt counts stages only.
__global__ __launch_bounds__(256, 2) void attn8(const ushort_t* __restrict__ Qh,
                                                const ushort_t* __restrict__ Kh,
                                                const ushort_t* __restrict__ VtG,
                                                ushort_t* __restrict__ aout) {
    __shared__ ushort_t Kb[3][64 * 64];
    __shared__ ushort_t Vb[3][64 * 64];
    int tid = threadIdx.x, lane = tid & 63, w = tid >> 6;
    int quad = lane >> 4, l15 = lane & 15;
    int bh = blockIdx.y;
    int qa = blockIdx.x;        // 0..15
    int qc = 31 - qa;           // 16..31
    const ushort_t* Qp = Qh + (size_t)bh * NN * HDD;
    const ushort_t* Kp = Kh + (size_t)bh * NN * HDD;
    const ushort_t* Vp = VtG + (size_t)bh * HDD * NN;
    int ra = qa * 64 + w * 16;
    int rc = qc * 64 + w * 16;

    bf16x8 aqa[2], aqc[2];
    for (int kc = 0; kc < 2; kc++) {
        aqa[kc] = *(const bf16x8*)&Qp[(size_t)(ra + l15) * HDD + kc * 32 + quad * 8];
        aqc[kc] = *(const bf16x8*)&Qp[(size_t)(rc + l15) * HDD + kc * 32 + quad * 8];
    }
    // Materialize Q fragments now: forces their vmem waits to retire BEFORE
    // the staging prologue, keeping in-loop vmcnt arithmetic stage-only.
    asm volatile("" :: "v"(aqa[0]), "v"(aqa[1]), "v"(aqc[0]), "v"(aqc[1]));

    f32x4 oa[4], oc[4];
    for (int ct = 0; ct < 4; ct++) {
        oa[ct] = (f32x4){0.f, 0.f, 0.f, 0.f};
        oc[ct] = (f32x4){0.f, 0.f, 0.f, 0.f};
    }
    float la = 0.f, lc = 0.f;

    int sr0 = tid >> 3, scg = tid & 7;
    int sr1 = sr0 + 32;
    int ssc = scg ^ (sr0 & 7);
    int key = l15 & 7;
    int c0 = (quad ^ key) * 8;
    int c1 = ((4 + quad) ^ key) * 8;

    auto stageK = [&](int s, int kt) {   // 4 gl_lds16 per thread per stage
        gl_lds16(Kp + (size_t)(kt * 64 + sr0) * 64 + ssc * 8, &Kb[s][(0 * 256 + w * 64) * 8]);
        gl_lds16(Kp + (size_t)(kt * 64 + sr1) * 64 + ssc * 8, &Kb[s][(1 * 256 + w * 64) * 8]);
        gl_lds16(Vp + (size_t)sr0 * NN + kt * 64 + ssc * 8, &Vb[s][(0 * 256 + w * 64) * 8]);
        gl_lds16(Vp + (size_t)sr1 * NN + kt * 64 + ssc * 8, &Vb[s][(1 * 256 + w * 64) * 8]);
    };
    stageK(0, 0);
    stageK(1, 1);          // qc >= 16, always valid

    int cur = 0;
    for (int kb = 0; kb <= qc; kb++) {
        if (kb < qc)
            asm volatile("s_waitcnt vmcnt(4)\ns_barrier" ::: "memory");
        else
            asm volatile("s_waitcnt vmcnt(0)\ns_barrier" ::: "memory");
        if (kb + 2 <= qc) stageK(cur == 0 ? 2 : cur - 1, kb + 2);  // (kb+2)%3
        bool da = (kb <= qa);

        bf16x8 kf0[4], kf1[4];
        for (int nt = 0; nt < 4; nt++) {
            kf0[nt] = *(const bf16x8*)&Kb[cur][(nt * 16 + l15) * 64 + c0];
            kf1[nt] = *(const bf16x8*)&Kb[cur][(nt * 16 + l15) * 64 + c1];
        }
        f16x4 vf[4][4];
        for (int ct = 0; ct < 4; ct++)
            for (int nt = 0; nt < 4; nt++)
                vf[ct][nt] = *(const f16x4*)&Vb[cur][(ct * 16 + l15) * 64 +
                                ((2 * nt + (quad >> 1)) ^ key) * 8 + (quad & 1) * 4];

        {
            f32x4 s[4];
            __builtin_amdgcn_s_setprio(1);
            for (int nt = 0; nt < 4; nt++) {
                f32x4 z = (f32x4){0.f, 0.f, 0.f, 0.f};
                z = MFMA32(kf0[nt], aqc[0], z);
                s[nt] = MFMA32(kf1[nt], aqc[1], z);
            }
            __builtin_amdgcn_s_setprio(0);
            f16x4 ap[4];
            if (kb == qc) {
                for (int nt = 0; nt < 4; nt++)
                    for (int r = 0; r < 4; r++) {
                        int kv = kb * 64 + nt * 16 + quad * 4 + r;
                        float p = (kv <= rc + l15) ? exp2f(s[nt][r]) : 0.f;
                        ap[nt][r] = (_Float16)p; lc += p;
                    }
            } else {
                for (int nt = 0; nt < 4; nt++)
                    for (int r = 0; r < 4; r++) {
                        float p = exp2f(s[nt][r]);
                        ap[nt][r] = (_Float16)p; lc += p;
                    }
            }
            __builtin_amdgcn_s_setprio(1);
            for (int ct = 0; ct < 4; ct++)
                for (int nt = 0; nt < 4; nt++)
                    oc[ct] = MFMA16H(ap[nt], vf[ct][nt], oc[ct]);
            __builtin_amdgcn_s_setprio(0);
        }
        if (da) {
            f32x4 s[4];
            __builtin_amdgcn_s_setprio(1);
            for (int nt = 0; nt < 4; nt++) {
                f32x4 z = (f32x4){0.f, 0.f, 0.f, 0.f};
                z = MFMA32(kf0[nt], aqa[0], z);
                s[nt] = MFMA32(kf1[nt], aqa[1], z);
            }
            __builtin_amdgcn_s_setprio(0);
            f16x4 ap[4];
            if (kb == qa) {
                for (int nt = 0; nt < 4; nt++)
                    for (int r = 0; r < 4; r++) {
                        int kv = kb * 64 + nt * 16 + quad * 4 + r;
                        float p = (kv <= ra + l15) ? exp2f(s[nt][r]) : 0.f;
                        ap[nt][r] = (_Float16)p; la += p;
                    }
            } else {
                for (int nt = 0; nt < 4; nt++)
                    for (int r = 0; r < 4; r++) {
                        float p = exp2f(s[nt][r]);
                        ap[nt][r] = (_Float16)p; la += p;
                    }
            }
            __builtin_amdgcn_s_setprio(1);
            for (int ct = 0; ct < 4; ct++)
                for (int nt = 0; nt < 4; nt++)
                    oa[ct] = MFMA16H(ap[nt], vf[ct][nt], oa[ct]);
            __builtin_amdgcn_s_setprio(0);
        }
        cur = (cur == 2) ? 0 : cur + 1;
    }

    la += __shfl_xor(la, 16); la += __shfl_xor(la, 32);
    lc += __shfl_xor(lc, 16); lc += __shfl_xor(lc, 32);

    int b = bh >> 4, h = bh & 15;
    for (int r = 0; r < 4; r++) {
        float ila = 1.f / __shfl(la, quad * 4 + r);
        float ilc = 1.f / __shfl(lc, quad * 4 + r);
        for (int ct = 0; ct < 4; ct++) {
            int c = ct * 16 + l15;
            int qqa = ra + quad * 4 + r;
            int qqc = rc + quad * 4 + r;
            aout[((size_t)(b * NN + qqa)) * DIMD + h * HDD + c] = f2bf(oa[ct][r] * ila);
            aout[((size_t)(b * NN + qqc)) * DIMD + h * HDD + c] = f2bf(oc[ct][r] * ilc);
        }
    }
}

extern "C" void kernel_launch(void* const* d_in, const int* in_sizes, int n_in,
                              void* d_out, int out_size, void* d_ws, size_t ws_size,
                              hipStream_t stream) {
    const float* q  = (const float*)d_in[0];
    const float* k  = (const float*)d_in[1];
    const float* v  = (const float*)d_in[2];
    // d_in[3] mask: provably causal tril — hardcoded
    const float* Wq = (const float*)d_in[4];
    const float* bq = (const float*)d_in[5];
    const float* Wk = (const float*)d_in[6];
    const float* bk = (const float*)d_in[7];
    const float* Wv = (const float*)d_in[8];
    const float* bv = (const float*)d_in[9];
    const float* Wo = (const float*)d_in[10];
    const float* bo = (const float*)d_in[11];
    float* out = (float*)d_out;

    char* ws = (char*)d_ws;
    ushort_t* Abf  = (ushort_t*)(ws);                    // 24 MB: q,k,v bf16
    ushort_t* Wbf  = (ushort_t*)(ws + (24ull << 20));    // 8 MB: Wq*SC2,Wk,Wv,Wo bf16
    ushort_t* Qh   = (ushort_t*)(ws + (32ull << 20));    // 8 MB [bh][n][c] bf16 (pre-scaled)
    ushort_t* Kh   = (ushort_t*)(ws + (40ull << 20));    // 8 MB [bh][n][c] bf16
    ushort_t* VtG  = (ushort_t*)(ws + (48ull << 20));    // 8 MB [bh][c][n] FP16
    ushort_t* AObf = (ushort_t*)(ws + (56ull << 20));    // 8 MB [4096][1024] bf16

    hipLaunchKernelGGL(convert_k, dim3(8192), dim3(256), 0, stream,
                       q, k, v, Wq, Wk, Wv, Wo, Abf, Wbf);
    hipLaunchKernelGGL((gemm_k<0, 128>), dim3(32, 8, 3), dim3(256), 0, stream,
                       Abf, Wbf, bq, bk, bv, Qh, Kh, VtG, (float*)nullptr);
    hipLaunchKernelGGL(attn8, dim3(16, 32), dim3(256), 0, stream, Qh, Kh, VtG, AObf);
    hipLaunchKernelGGL((gemm_k<1, 64>), dim3(64, 8, 1), dim3(256), 0, stream,
                       AObf, Wbf + 3ull * 1024 * 1024, bo, nullptr, nullptr,
                       nullptr, nullptr, nullptr, out);
}

// Round 6
// 221.041 us; speedup vs baseline: 1.1731x; 1.0406x over previous
//
#include <hip/hip_runtime.h>

#define NN 2048
#define DIMD 1024
#define HH 16
#define HDD 64
// SCALE * log2(e): folded into Wq/bq so S exits QK^T in exp2 domain
#define SC2 0.1803368801111244f

typedef __attribute__((ext_vector_type(8))) short bf16x8;
typedef __attribute__((ext_vector_type(4))) float f32x4;
typedef __attribute__((ext_vector_type(4))) _Float16 f16x4;
typedef __attribute__((ext_vector_type(2))) __fp16 hf16x2;   // cvt_pkrtz native type
typedef unsigned short ushort_t;
typedef unsigned int uint_t;

#define MFMA32(a, b, c) __builtin_amdgcn_mfma_f32_16x16x32_bf16((a), (b), (c), 0, 0, 0)
// legacy-name f16 K=16 MFMA (compiler-suggested spelling on this toolchain)
#define MFMA16H(a, b, c) __builtin_amdgcn_mfma_f32_16x16x16f16((a), (b), (c), 0, 0, 0)

__device__ __forceinline__ ushort_t f2bf(float f) {   // RNE
    union { float f; uint_t u; } v; v.f = f;
    uint_t u = v.u;
    return (ushort_t)((u + 0x7FFFu + ((u >> 16) & 1u)) >> 16);
}
__device__ __forceinline__ void gl_lds16(const ushort_t* g, ushort_t* l) {
    __builtin_amdgcn_global_load_lds(
        (const __attribute__((address_space(1))) void*)g,
        (__attribute__((address_space(3))) void*)l, 16, 0, 0);
}

// ---- fp32 -> bf16: q,k,v (3x4M) -> Abf ; Wq*SC2,Wk,Wv,Wo (4x1M) -> Wbf
__global__ __launch_bounds__(256) void convert_k(
    const float* __restrict__ q, const float* __restrict__ k, const float* __restrict__ v,
    const float* __restrict__ wq, const float* __restrict__ wk,
    const float* __restrict__ wv, const float* __restrict__ wo,
    ushort_t* __restrict__ Abf, ushort_t* __restrict__ Wbf) {
    size_t gid = (size_t)blockIdx.x * 256 + threadIdx.x;
    size_t e = gid * 8;
    const float* src; ushort_t* dst;
    float sc = 1.f;
    if (e < 12582912) {
        int i = (int)(e >> 22);
        src = (i == 0 ? q : (i == 1 ? k : v)) + (e & 4194303);
        dst = Abf + e;
    } else {
        size_t e2 = e - 12582912;
        int i = (int)(e2 >> 20);
        src = (i == 0 ? wq : (i == 1 ? wk : (i == 2 ? wv : wo))) + (e2 & 1048575);
        dst = Wbf + e2;
        if (i == 0) sc = SC2;
    }
    float4 x = ((const float4*)src)[0], y = ((const float4*)src)[1];
    union { uint4 u; ushort_t s[8]; } pk;
    pk.s[0] = f2bf(x.x * sc); pk.s[1] = f2bf(x.y * sc); pk.s[2] = f2bf(x.z * sc); pk.s[3] = f2bf(x.w * sc);
    pk.s[4] = f2bf(y.x * sc); pk.s[5] = f2bf(y.y * sc); pk.s[6] = f2bf(y.z * sc); pk.s[7] = f2bf(y.w * sc);
    *(uint4*)dst = pk.u;
}

// ---- dbuf bf16 GEMM, TM x 128 tile, BK=32, conflict-free XOR-swizzled LDS.
// TM=128: 64x64 wave tiles (2x2 waves) -> 0.5 ds_read per MFMA (LDS-BW optimized,
//         3 blocks/CU). TM=64: 32x64 wave tiles (grid doubles; for the O-proj
//         whose N=1024 grid would otherwise leave CUs empty).
// MODE 0: z-batched QKV -> split-head (z=0 Q bf16 bias*SC2; z=1 K bf16;
//         z=2 V^T [bh][c][n] FP16, packed 8B).  MODE 1: out proj -> fp32.
template<int MODE, int TM>
__global__ __launch_bounds__(256, TM == 128 ? 3 : 5) void gemm_k(
    const ushort_t* __restrict__ Abase, const ushort_t* __restrict__ Wbase,
    const float* __restrict__ b0p, const float* __restrict__ b1p, const float* __restrict__ b2p,
    ushort_t* __restrict__ d0, ushort_t* __restrict__ d1, ushort_t* __restrict__ d2,
    float* __restrict__ fout) {
    const int K = 1024;
    constexpr int MT = TM / 32;          // m-tiles (16-row) per wave
    __shared__ ushort_t As[2][TM * 32];
    __shared__ ushort_t Bs[2][128 * 32];
    int z = (MODE == 0) ? blockIdx.z : 0;
    const ushort_t* A = Abase + (size_t)z * 4096 * 1024;
    const ushort_t* W = Wbase + (size_t)z * 1024 * 1024;
    const float* bias = (MODE == 0) ? (z == 0 ? b0p : (z == 1 ? b1p : b2p)) : b0p;
    int tid = threadIdx.x;
    int m0 = blockIdx.x * TM, n0 = blockIdx.y * 128;
    int lane = tid & 63, wave = tid >> 6;
    int quad = lane >> 4, l15 = lane & 15;
    int wm = (wave >> 1) * (TM / 2), wn = (wave & 1) * 64;

    f32x4 acc[MT][4];
    for (int i = 0; i < MT; i++)
        for (int j = 0; j < 4; j++)
            acc[i][j] = (f32x4){0.f, 0.f, 0.f, 0.f};

    // staging: slot (row, c) holds global chunk c ^ ((row>>1)&3)   (rows of 4x16B)
    int rA = tid >> 2, cA = tid & 3;
    int gA = cA ^ ((rA >> 1) & 3);       // (rA+64) gives the same key: 64>>1 ≡ 0 mod 4

    auto stage = [&](int buf, int k0) {
        gl_lds16(A + (size_t)(m0 + rA) * K + k0 + gA * 8, &As[buf][tid * 8]);
        if (TM == 128)
            gl_lds16(A + (size_t)(m0 + rA + 64) * K + k0 + gA * 8, &As[buf][(tid + 256) * 8]);
        gl_lds16(W + (size_t)(n0 + rA) * K + k0 + gA * 8, &Bs[buf][tid * 8]);
        gl_lds16(W + (size_t)(n0 + rA + 64) * K + k0 + gA * 8, &Bs[buf][(tid + 256) * 8]);
    };
    stage(0, 0);

    // fragment chunk: rows are base+l15 (base mult of 16) -> key = (l15>>1)&3
    int fc = (quad ^ ((l15 >> 1) & 3)) * 8;

    for (int it = 0; it < 32; it++) {
        int cur = it & 1;
        __syncthreads();   // drains stage(it) — issued a full compute-phase ago
        if (it < 31) stage(1 - cur, (it + 1) * 32);
        bf16x8 a[MT], b[4];
        for (int mt = 0; mt < MT; mt++)
            a[mt] = *(const bf16x8*)&As[cur][(wm + mt * 16 + l15) * 32 + fc];
        for (int nt = 0; nt < 4; nt++)
            b[nt] = *(const bf16x8*)&Bs[cur][(wn + nt * 16 + l15) * 32 + fc];
        for (int mt = 0; mt < MT; mt++)
            for (int nt = 0; nt < 4; nt++)
                acc[mt][nt] = MFMA32(a[mt], b[nt], acc[mt][nt]);
    }
    // D mapping: col(n)=lane&15, row(m)=quad*4+reg
    if (MODE == 0 && z == 2) {
        // V^T [bh][c][n] as FP16, packed 8B stores (4 consecutive seq positions)
        for (int nt = 0; nt < 4; nt++) {
            int n = n0 + wn + nt * 16 + l15;
            float bv = bias[n];
            int h = n >> 6, c = n & 63;
            for (int mt = 0; mt < MT; mt++) {
                int mb = m0 + wm + mt * 16 + quad * 4;
                int b = mb >> 11, ns = mb & 2047;
                union { uint2 u2; _Float16 hh[4]; } pkv;
                pkv.hh[0] = (_Float16)(acc[mt][nt][0] + bv);
                pkv.hh[1] = (_Float16)(acc[mt][nt][1] + bv);
                pkv.hh[2] = (_Float16)(acc[mt][nt][2] + bv);
                pkv.hh[3] = (_Float16)(acc[mt][nt][3] + bv);
                *(uint2*)&d2[(((size_t)(b * HH + h)) * HDD + c) * NN + ns] = pkv.u2;
            }
        }
    } else {
        for (int nt = 0; nt < 4; nt++) {
            int n = n0 + wn + nt * 16 + l15;
            float bv = bias[n];
            if (MODE == 0 && z == 0) bv *= SC2;
            for (int mt = 0; mt < MT; mt++)
                for (int r = 0; r < 4; r++) {
                    int m = m0 + wm + mt * 16 + quad * 4 + r;
                    float val = acc[mt][nt][r] + bv;
                    if (MODE == 0) {
                        int b = m >> 11, ns = m & 2047;
                        int h = n >> 6, c = n & 63;
                        ushort_t* dst = (z == 0) ? d0 : d1;
                        dst[(((size_t)(b * HH + h)) * NN + ns) * HDD + c] = f2bf(val);
                    } else {
                        fout[(size_t)m * DIMD + n] = val;
                    }
                }
        }
    }
}

// ---- flash attention, causal. Round 6 = round 5 with the cvt_pkrtz type fix
// (union member is the builtin's native __fp16 vec2; same bits as f16x4).
// Changes vs verified attn5/attn8 base:
//  * KVBLK 64->128: each dbuf slot holds two 64-wide K/V panels; barrier
//    count halves (<=32 -> <=16 iters).
//  * row-sums l via MFMA-with-ones into ol (kills the 32-deep serial v_add
//    chain AND the epilogue shfl reduction; moves work VALU->MFMA pipe).
//  * __builtin_amdgcn_exp2f + cvt_pkrtz packed f32->f16x2 (halves
//    conversion/packing VALU).
// Counters r1-r4: VALUBusy ~39% = 2x MfmaUtil ~19% at 2 waves/SIMD — the
// per-wave VALU stream is the plateau; this attacks it directly.
__global__ __launch_bounds__(256, 2) void attn9(const ushort_t* __restrict__ Qh,
                                                const ushort_t* __restrict__ Kh,
                                                const ushort_t* __restrict__ VtG,
                                                ushort_t* __restrict__ aout) {
    __shared__ ushort_t Kb[2][2][64 * 64];   // [dbuf][64-row half][64x64 panel]
    __shared__ ushort_t Vb[2][2][64 * 64];   // [dbuf][64-col half][64x64 panel]
    int tid = threadIdx.x, lane = tid & 63, w = tid >> 6;
    int quad = lane >> 4, l15 = lane & 15;
    int bh = blockIdx.y;
    int qa = blockIdx.x;        // 0..15
    int qc = 31 - qa;           // 16..31
    const ushort_t* Qp = Qh + (size_t)bh * NN * HDD;
    const ushort_t* Kp = Kh + (size_t)bh * NN * HDD;
    const ushort_t* Vp = VtG + (size_t)bh * HDD * NN;
    int ra = qa * 64 + w * 16;
    int rc = qc * 64 + w * 16;

    bf16x8 aqa[2], aqc[2];
    for (int kk = 0; kk < 2; kk++) {
        aqa[kk] = *(const bf16x8*)&Qp[(size_t)(ra + l15) * HDD + kk * 32 + quad * 8];
        aqc[kk] = *(const bf16x8*)&Qp[(size_t)(rc + l15) * HDD + kk * 32 + quad * 8];
    }
    asm volatile("" :: "v"(aqa[0]), "v"(aqa[1]), "v"(aqc[0]), "v"(aqc[1]));

    f32x4 oa[4], oc[4], ola, olc;
    for (int ct = 0; ct < 4; ct++) {
        oa[ct] = (f32x4){0.f, 0.f, 0.f, 0.f};
        oc[ct] = (f32x4){0.f, 0.f, 0.f, 0.f};
    }
    ola = (f32x4){0.f, 0.f, 0.f, 0.f};
    olc = (f32x4){0.f, 0.f, 0.f, 0.f};
    const f16x4 vone = {(_Float16)1.f, (_Float16)1.f, (_Float16)1.f, (_Float16)1.f};

    int sr0 = tid >> 3, scg = tid & 7;     // sr0 in [0,32)
    int ssc = scg ^ (sr0 & 7);
    int key = l15 & 7;
    int c0 = (quad ^ key) * 8;
    int c1 = ((4 + quad) ^ key) * 8;

    // stage k-block kt (128 kv rows) into slot s: K two 64-row panels,
    // V two 64-col panels; per-row chunk-XOR layout identical to r1 kernel.
    auto stageK = [&](int s, int kt) {     // 8 gl_lds16 per thread
        for (int h = 0; h < 2; h++) {
            int kr = kt * 128 + h * 64;
            gl_lds16(Kp + (size_t)(kr + sr0) * HDD + ssc * 8,      &Kb[s][h][(0 * 256 + w * 64) * 8]);
            gl_lds16(Kp + (size_t)(kr + sr0 + 32) * HDD + ssc * 8, &Kb[s][h][(1 * 256 + w * 64) * 8]);
            gl_lds16(Vp + (size_t)sr0 * NN + kr + ssc * 8,         &Vb[s][h][(0 * 256 + w * 64) * 8]);
            gl_lds16(Vp + (size_t)(sr0 + 32) * NN + kr + ssc * 8,  &Vb[s][h][(1 * 256 + w * 64) * 8]);
        }
    };

    int kbmax = qc >> 1;   // 8..15
    int kam   = qa >> 1;   // tile-a active while kb2 <= kam
    stageK(0, 0);

    // one 64-wide kv panel for one q-tile
    auto doHalf = [&](const bf16x8 (&aq)[2], f32x4 (&o)[4], f32x4& ol,
                      int rowb, const ushort_t* Kl, const ushort_t* Vl,
                      int kvb, bool diag) {
        bf16x8 kf0[4], kf1[4];
        for (int nt = 0; nt < 4; nt++) {
            kf0[nt] = *(const bf16x8*)&Kl[(nt * 16 + l15) * 64 + c0];
            kf1[nt] = *(const bf16x8*)&Kl[(nt * 16 + l15) * 64 + c1];
        }
        f32x4 s[4];
        __builtin_amdgcn_s_setprio(1);
        for (int nt = 0; nt < 4; nt++) {
            f32x4 z = (f32x4){0.f, 0.f, 0.f, 0.f};
            z = MFMA32(kf0[nt], aq[0], z);
            s[nt] = MFMA32(kf1[nt], aq[1], z);
        }
        __builtin_amdgcn_s_setprio(0);
        f16x4 ap[4];
        if (diag) {
            for (int nt = 0; nt < 4; nt++) {
                float pp[4];
                for (int r = 0; r < 4; r++) {
                    int kv = kvb + nt * 16 + quad * 4 + r;
                    pp[r] = (kv <= rowb + l15) ? __builtin_amdgcn_exp2f(s[nt][r]) : 0.f;
                }
                union { hf16x2 h2[2]; f16x4 h4; } u;
                u.h2[0] = __builtin_amdgcn_cvt_pkrtz(pp[0], pp[1]);
                u.h2[1] = __builtin_amdgcn_cvt_pkrtz(pp[2], pp[3]);
                ap[nt] = u.h4;
            }
        } else {
            for (int nt = 0; nt < 4; nt++) {
                union { hf16x2 h2[2]; f16x4 h4; } u;
                u.h2[0] = __builtin_amdgcn_cvt_pkrtz(__builtin_amdgcn_exp2f(s[nt][0]),
                                                     __builtin_amdgcn_exp2f(s[nt][1]));
                u.h2[1] = __builtin_amdgcn_cvt_pkrtz(__builtin_amdgcn_exp2f(s[nt][2]),
                                                     __builtin_amdgcn_exp2f(s[nt][3]));
                ap[nt] = u.h4;
            }
        }
        f16x4 vf[4][4];
        for (int ct = 0; ct < 4; ct++)
            for (int nt = 0; nt < 4; nt++)
                vf[ct][nt] = *(const f16x4*)&Vl[(ct * 16 + l15) * 64 +
                                ((2 * nt + (quad >> 1)) ^ key) * 8 + (quad & 1) * 4];
        __builtin_amdgcn_s_setprio(1);
        for (int nt = 0; nt < 4; nt++)
            ol = MFMA16H(ap[nt], vone, ol);        // row-sum of P (every lane)
        for (int ct = 0; ct < 4; ct++)
            for (int nt = 0; nt < 4; nt++)
                o[ct] = MFMA16H(ap[nt], vf[ct][nt], o[ct]);
        __builtin_amdgcn_s_setprio(0);
    };

    int cur = 0;
    for (int kb2 = 0; kb2 <= kbmax; kb2++) {
        __syncthreads();                     // drains stage(kb2)
        if (kb2 < kbmax) stageK(cur ^ 1, kb2 + 1);
        bool dc = (kb2 == kbmax);            // tile-c diagonal k-block
        for (int h = 0; h < 2; h++)
            doHalf(aqc, oc, olc, rc, &Kb[cur][h][0], &Vb[cur][h][0],
                   kb2 * 128 + h * 64, dc);
        if (kb2 <= kam) {
            bool da = (kb2 == kam);          // tile-a diagonal k-block
            for (int h = 0; h < 2; h++)
                doHalf(aqa, oa, ola, ra, &Kb[cur][h][0], &Vb[cur][h][0],
                       kb2 * 128 + h * 64, da);
        }
        cur ^= 1;
    }

    int b = bh >> 4, h = bh & 15;
    for (int r = 0; r < 4; r++) {
        float ila = 1.f / ola[r];            // full row sum — no shuffles needed
        float ilc = 1.f / olc[r];
        for (int ct = 0; ct < 4; ct++) {
            int c = ct * 16 + l15;
            int qqa = ra + quad * 4 + r;
            int qqc = rc + quad * 4 + r;
            aout[((size_t)(b * NN + qqa)) * DIMD + h * HDD + c] = f2bf(oa[ct][r] * ila);
            aout[((size_t)(b * NN + qqc)) * DIMD + h * HDD + c] = f2bf(oc[ct][r] * ilc);
        }
    }
}

extern "C" void kernel_launch(void* const* d_in, const int* in_sizes, int n_in,
                              void* d_out, int out_size, void* d_ws, size_t ws_size,
                              hipStream_t stream) {
    const float* q  = (const float*)d_in[0];
    const float* k  = (const float*)d_in[1];
    const float* v  = (const float*)d_in[2];
    // d_in[3] mask: provably causal tril — hardcoded
    const float* Wq = (const float*)d_in[4];
    const float* bq = (const float*)d_in[5];
    const float* Wk = (const float*)d_in[6];
    const float* bk = (const float*)d_in[7];
    const float* Wv = (const float*)d_in[8];
    const float* bv = (const float*)d_in[9];
    const float* Wo = (const float*)d_in[10];
    const float* bo = (const float*)d_in[11];
    float* out = (float*)d_out;

    char* ws = (char*)d_ws;
    ushort_t* Abf  = (ushort_t*)(ws);                    // 24 MB: q,k,v bf16
    ushort_t* Wbf  = (ushort_t*)(ws + (24ull << 20));    // 8 MB: Wq*SC2,Wk,Wv,Wo bf16
    ushort_t* Qh   = (ushort_t*)(ws + (32ull << 20));    // 8 MB [bh][n][c] bf16 (pre-scaled)
    ushort_t* Kh   = (ushort_t*)(ws + (40ull << 20));    // 8 MB [bh][n][c] bf16
    ushort_t* VtG  = (ushort_t*)(ws + (48ull << 20));    // 8 MB [bh][c][n] FP16
    ushort_t* AObf = (ushort_t*)(ws + (56ull << 20));    // 8 MB [4096][1024] bf16

    hipLaunchKernelGGL(convert_k, dim3(8192), dim3(256), 0, stream,
                       q, k, v, Wq, Wk, Wv, Wo, Abf, Wbf);
    hipLaunchKernelGGL((gemm_k<0, 128>), dim3(32, 8, 3), dim3(256), 0, stream,
                       Abf, Wbf, bq, bk, bv, Qh, Kh, VtG, (float*)nullptr);
    hipLaunchKernelGGL(attn9, dim3(16, 32), dim3(256), 0, stream, Qh, Kh, VtG, AObf);
    hipLaunchKernelGGL((gemm_k<1, 64>), dim3(64, 8, 1), dim3(256), 0, stream,
                       AObf, Wbf + 3ull * 1024 * 1024, bo, nullptr, nullptr,
                       nullptr, nullptr, nullptr, out);
}

// Round 7
// 220.073 us; speedup vs baseline: 1.1783x; 1.0044x over previous
//
#include <hip/hip_runtime.h>

#define NN 2048
#define DIMD 1024
#define HH 16
#define HDD 64
// SCALE * log2(e): folded into Wq/bq so S exits QK^T in exp2 domain
#define SC2 0.1803368801111244f

typedef __attribute__((ext_vector_type(8))) short bf16x8;
typedef __attribute__((ext_vector_type(4))) float f32x4;
typedef __attribute__((ext_vector_type(4))) _Float16 f16x4;
typedef __attribute__((ext_vector_type(2))) __fp16 hf16x2;   // cvt_pkrtz native type
typedef unsigned short ushort_t;
typedef unsigned int uint_t;

#define MFMA32(a, b, c) __builtin_amdgcn_mfma_f32_16x16x32_bf16((a), (b), (c), 0, 0, 0)
// legacy-name f16 K=16 MFMA (compiler-suggested spelling on this toolchain)
#define MFMA16H(a, b, c) __builtin_amdgcn_mfma_f32_16x16x16f16((a), (b), (c), 0, 0, 0)

__device__ __forceinline__ ushort_t f2bf(float f) {   // RNE
    union { float f; uint_t u; } v; v.f = f;
    uint_t u = v.u;
    return (ushort_t)((u + 0x7FFFu + ((u >> 16) & 1u)) >> 16);
}
__device__ __forceinline__ void gl_lds16(const ushort_t* g, ushort_t* l) {
    __builtin_amdgcn_global_load_lds(
        (const __attribute__((address_space(1))) void*)g,
        (__attribute__((address_space(3))) void*)l, 16, 0, 0);
}

// ---- fp32 -> bf16: q,k,v (3x4M) -> Abf ; Wq*SC2,Wk,Wv,Wo (4x1M) -> Wbf
__global__ __launch_bounds__(256) void convert_k(
    const float* __restrict__ q, const float* __restrict__ k, const float* __restrict__ v,
    const float* __restrict__ wq, const float* __restrict__ wk,
    const float* __restrict__ wv, const float* __restrict__ wo,
    ushort_t* __restrict__ Abf, ushort_t* __restrict__ Wbf) {
    size_t gid = (size_t)blockIdx.x * 256 + threadIdx.x;
    size_t e = gid * 8;
    const float* src; ushort_t* dst;
    float sc = 1.f;
    if (e < 12582912) {
        int i = (int)(e >> 22);
        src = (i == 0 ? q : (i == 1 ? k : v)) + (e & 4194303);
        dst = Abf + e;
    } else {
        size_t e2 = e - 12582912;
        int i = (int)(e2 >> 20);
        src = (i == 0 ? wq : (i == 1 ? wk : (i == 2 ? wv : wo))) + (e2 & 1048575);
        dst = Wbf + e2;
        if (i == 0) sc = SC2;
    }
    float4 x = ((const float4*)src)[0], y = ((const float4*)src)[1];
    union { uint4 u; ushort_t s[8]; } pk;
    pk.s[0] = f2bf(x.x * sc); pk.s[1] = f2bf(x.y * sc); pk.s[2] = f2bf(x.z * sc); pk.s[3] = f2bf(x.w * sc);
    pk.s[4] = f2bf(y.x * sc); pk.s[5] = f2bf(y.y * sc); pk.s[6] = f2bf(y.z * sc); pk.s[7] = f2bf(y.w * sc);
    *(uint4*)dst = pk.u;
}

// ---- dbuf bf16 GEMM, TM x 128 tile, BK=32, conflict-free XOR-swizzled LDS.
// TM=128: 64x64 wave tiles (2x2 waves) -> 0.5 ds_read per MFMA (LDS-BW optimized,
//         3 blocks/CU). TM=64: 32x64 wave tiles (grid doubles; for the O-proj
//         whose N=1024 grid would otherwise leave CUs empty).
// MODE 0: z-batched QKV -> split-head (z=0 Q bf16 bias*SC2; z=1 K bf16;
//         z=2 V^T [bh][c][n] FP16, packed 8B).  MODE 1: out proj -> fp32.
template<int MODE, int TM>
__global__ __launch_bounds__(256, TM == 128 ? 3 : 5) void gemm_k(
    const ushort_t* __restrict__ Abase, const ushort_t* __restrict__ Wbase,
    const float* __restrict__ b0p, const float* __restrict__ b1p, const float* __restrict__ b2p,
    ushort_t* __restrict__ d0, ushort_t* __restrict__ d1, ushort_t* __restrict__ d2,
    float* __restrict__ fout) {
    const int K = 1024;
    constexpr int MT = TM / 32;          // m-tiles (16-row) per wave
    __shared__ ushort_t As[2][TM * 32];
    __shared__ ushort_t Bs[2][128 * 32];
    int z = (MODE == 0) ? blockIdx.z : 0;
    const ushort_t* A = Abase + (size_t)z * 4096 * 1024;
    const ushort_t* W = Wbase + (size_t)z * 1024 * 1024;
    const float* bias = (MODE == 0) ? (z == 0 ? b0p : (z == 1 ? b1p : b2p)) : b0p;
    int tid = threadIdx.x;
    int m0 = blockIdx.x * TM, n0 = blockIdx.y * 128;
    int lane = tid & 63, wave = tid >> 6;
    int quad = lane >> 4, l15 = lane & 15;
    int wm = (wave >> 1) * (TM / 2), wn = (wave & 1) * 64;

    f32x4 acc[MT][4];
    for (int i = 0; i < MT; i++)
        for (int j = 0; j < 4; j++)
            acc[i][j] = (f32x4){0.f, 0.f, 0.f, 0.f};

    // staging: slot (row, c) holds global chunk c ^ ((row>>1)&3)   (rows of 4x16B)
    int rA = tid >> 2, cA = tid & 3;
    int gA = cA ^ ((rA >> 1) & 3);       // (rA+64) gives the same key: 64>>1 ≡ 0 mod 4

    auto stage = [&](int buf, int k0) {
        gl_lds16(A + (size_t)(m0 + rA) * K + k0 + gA * 8, &As[buf][tid * 8]);
        if (TM == 128)
            gl_lds16(A + (size_t)(m0 + rA + 64) * K + k0 + gA * 8, &As[buf][(tid + 256) * 8]);
        gl_lds16(W + (size_t)(n0 + rA) * K + k0 + gA * 8, &Bs[buf][tid * 8]);
        gl_lds16(W + (size_t)(n0 + rA + 64) * K + k0 + gA * 8, &Bs[buf][(tid + 256) * 8]);
    };
    stage(0, 0);

    // fragment chunk: rows are base+l15 (base mult of 16) -> key = (l15>>1)&3
    int fc = (quad ^ ((l15 >> 1) & 3)) * 8;

    for (int it = 0; it < 32; it++) {
        int cur = it & 1;
        __syncthreads();   // drains stage(it) — issued a full compute-phase ago
        if (it < 31) stage(1 - cur, (it + 1) * 32);
        bf16x8 a[MT], b[4];
        for (int mt = 0; mt < MT; mt++)
            a[mt] = *(const bf16x8*)&As[cur][(wm + mt * 16 + l15) * 32 + fc];
        for (int nt = 0; nt < 4; nt++)
            b[nt] = *(const bf16x8*)&Bs[cur][(wn + nt * 16 + l15) * 32 + fc];
        for (int mt = 0; mt < MT; mt++)
            for (int nt = 0; nt < 4; nt++)
                acc[mt][nt] = MFMA32(a[mt], b[nt], acc[mt][nt]);
    }
    // D mapping: col(n)=lane&15, row(m)=quad*4+reg
    if (MODE == 0 && z == 2) {
        // V^T [bh][c][n] as FP16, packed 8B stores (4 consecutive seq positions)
        for (int nt = 0; nt < 4; nt++) {
            int n = n0 + wn + nt * 16 + l15;
            float bv = bias[n];
            int h = n >> 6, c = n & 63;
            for (int mt = 0; mt < MT; mt++) {
                int mb = m0 + wm + mt * 16 + quad * 4;
                int b = mb >> 11, ns = mb & 2047;
                union { uint2 u2; _Float16 hh[4]; } pkv;
                pkv.hh[0] = (_Float16)(acc[mt][nt][0] + bv);
                pkv.hh[1] = (_Float16)(acc[mt][nt][1] + bv);
                pkv.hh[2] = (_Float16)(acc[mt][nt][2] + bv);
                pkv.hh[3] = (_Float16)(acc[mt][nt][3] + bv);
                *(uint2*)&d2[(((size_t)(b * HH + h)) * HDD + c) * NN + ns] = pkv.u2;
            }
        }
    } else {
        for (int nt = 0; nt < 4; nt++) {
            int n = n0 + wn + nt * 16 + l15;
            float bv = bias[n];
            if (MODE == 0 && z == 0) bv *= SC2;
            for (int mt = 0; mt < MT; mt++)
                for (int r = 0; r < 4; r++) {
                    int m = m0 + wm + mt * 16 + quad * 4 + r;
                    float val = acc[mt][nt][r] + bv;
                    if (MODE == 0) {
                        int b = m >> 11, ns = m & 2047;
                        int h = n >> 6, c = n & 63;
                        ushort_t* dst = (z == 0) ? d0 : d1;
                        dst[(((size_t)(b * HH + h)) * NN + ns) * HDD + c] = f2bf(val);
                    } else {
                        fout[(size_t)m * DIMD + n] = val;
                    }
                }
        }
    }
}

// ---- flash attention, causal. Round 7: attn9 + restored kf/vf SHARING
// across the two q-tiles (the r5 doHalf refactor re-read identical K/V
// fragments from LDS twice on shared k-blocks; r6 counters show the LDS
// read pipe is now the largest consumer ~50% of CU cycles vs MFMA 28%).
// Fragments are loaded once per 64-panel and feed both tiles' compute —
// bit-identical semantics, ~20% less LDS-read traffic.
__global__ __launch_bounds__(256, 2) void attn10(const ushort_t* __restrict__ Qh,
                                                 const ushort_t* __restrict__ Kh,
                                                 const ushort_t* __restrict__ VtG,
                                                 ushort_t* __restrict__ aout) {
    __shared__ ushort_t Kb[2][2][64 * 64];   // [dbuf][64-row half][64x64 panel]
    __shared__ ushort_t Vb[2][2][64 * 64];   // [dbuf][64-col half][64x64 panel]
    int tid = threadIdx.x, lane = tid & 63, w = tid >> 6;
    int quad = lane >> 4, l15 = lane & 15;
    int bh = blockIdx.y;
    int qa = blockIdx.x;        // 0..15
    int qc = 31 - qa;           // 16..31
    const ushort_t* Qp = Qh + (size_t)bh * NN * HDD;
    const ushort_t* Kp = Kh + (size_t)bh * NN * HDD;
    const ushort_t* Vp = VtG + (size_t)bh * HDD * NN;
    int ra = qa * 64 + w * 16;
    int rc = qc * 64 + w * 16;

    bf16x8 aqa[2], aqc[2];
    for (int kk = 0; kk < 2; kk++) {
        aqa[kk] = *(const bf16x8*)&Qp[(size_t)(ra + l15) * HDD + kk * 32 + quad * 8];
        aqc[kk] = *(const bf16x8*)&Qp[(size_t)(rc + l15) * HDD + kk * 32 + quad * 8];
    }
    asm volatile("" :: "v"(aqa[0]), "v"(aqa[1]), "v"(aqc[0]), "v"(aqc[1]));

    f32x4 oa[4], oc[4], ola, olc;
    for (int ct = 0; ct < 4; ct++) {
        oa[ct] = (f32x4){0.f, 0.f, 0.f, 0.f};
        oc[ct] = (f32x4){0.f, 0.f, 0.f, 0.f};
    }
    ola = (f32x4){0.f, 0.f, 0.f, 0.f};
    olc = (f32x4){0.f, 0.f, 0.f, 0.f};
    const f16x4 vone = {(_Float16)1.f, (_Float16)1.f, (_Float16)1.f, (_Float16)1.f};

    int sr0 = tid >> 3, scg = tid & 7;     // sr0 in [0,32)
    int ssc = scg ^ (sr0 & 7);
    int key = l15 & 7;
    int c0 = (quad ^ key) * 8;
    int c1 = ((4 + quad) ^ key) * 8;

    // stage k-block kt (128 kv rows) into slot s: K two 64-row panels,
    // V two 64-col panels; per-row chunk-XOR layout identical to r1 kernel.
    auto stageK = [&](int s, int kt) {     // 8 gl_lds16 per thread
        for (int h = 0; h < 2; h++) {
            int kr = kt * 128 + h * 64;
            gl_lds16(Kp + (size_t)(kr + sr0) * HDD + ssc * 8,      &Kb[s][h][(0 * 256 + w * 64) * 8]);
            gl_lds16(Kp + (size_t)(kr + sr0 + 32) * HDD + ssc * 8, &Kb[s][h][(1 * 256 + w * 64) * 8]);
            gl_lds16(Vp + (size_t)sr0 * NN + kr + ssc * 8,         &Vb[s][h][(0 * 256 + w * 64) * 8]);
            gl_lds16(Vp + (size_t)(sr0 + 32) * NN + kr + ssc * 8,  &Vb[s][h][(1 * 256 + w * 64) * 8]);
        }
    };

    int kbmax = qc >> 1;   // 8..15
    int kam   = qa >> 1;   // tile-a active while kb2 <= kam
    stageK(0, 0);

    // compute one q-tile against shared kf/vf fragments of one 64-panel
    auto computeTile = [&](const bf16x8 (&aq)[2], f32x4 (&o)[4], f32x4& ol,
                           int rowb, const bf16x8 (&kf0)[4], const bf16x8 (&kf1)[4],
                           const f16x4 (&vf)[4][4], int kvb, bool diag) {
        f32x4 s[4];
        __builtin_amdgcn_s_setprio(1);
        for (int nt = 0; nt < 4; nt++) {
            f32x4 z = (f32x4){0.f, 0.f, 0.f, 0.f};
            z = MFMA32(kf0[nt], aq[0], z);
            s[nt] = MFMA32(kf1[nt], aq[1], z);
        }
        __builtin_amdgcn_s_setprio(0);
        f16x4 ap[4];
        if (diag) {
            for (int nt = 0; nt < 4; nt++) {
                float pp[4];
                for (int r = 0; r < 4; r++) {
                    int kv = kvb + nt * 16 + quad * 4 + r;
                    pp[r] = (kv <= rowb + l15) ? __builtin_amdgcn_exp2f(s[nt][r]) : 0.f;
                }
                union { hf16x2 h2[2]; f16x4 h4; } u;
                u.h2[0] = __builtin_amdgcn_cvt_pkrtz(pp[0], pp[1]);
                u.h2[1] = __builtin_amdgcn_cvt_pkrtz(pp[2], pp[3]);
                ap[nt] = u.h4;
            }
        } else {
            for (int nt = 0; nt < 4; nt++) {
                union { hf16x2 h2[2]; f16x4 h4; } u;
                u.h2[0] = __builtin_amdgcn_cvt_pkrtz(__builtin_amdgcn_exp2f(s[nt][0]),
                                                     __builtin_amdgcn_exp2f(s[nt][1]));
                u.h2[1] = __builtin_amdgcn_cvt_pkrtz(__builtin_amdgcn_exp2f(s[nt][2]),
                                                     __builtin_amdgcn_exp2f(s[nt][3]));
                ap[nt] = u.h4;
            }
        }
        __builtin_amdgcn_s_setprio(1);
        for (int nt = 0; nt < 4; nt++)
            ol = MFMA16H(ap[nt], vone, ol);        // row-sum of P (every lane)
        for (int ct = 0; ct < 4; ct++)
            for (int nt = 0; nt < 4; nt++)
                o[ct] = MFMA16H(ap[nt], vf[ct][nt], o[ct]);
        __builtin_amdgcn_s_setprio(0);
    };

    int cur = 0;
    for (int kb2 = 0; kb2 <= kbmax; kb2++) {
        __syncthreads();                     // drains stage(kb2)
        if (kb2 < kbmax) stageK(cur ^ 1, kb2 + 1);
        bool act_a = (kb2 <= kam);
        bool dc = (kb2 == kbmax);
        bool da = (kb2 == kam);
        for (int h = 0; h < 2; h++) {
            const ushort_t* Kl = &Kb[cur][h][0];
            const ushort_t* Vl = &Vb[cur][h][0];
            int kvb = kb2 * 128 + h * 64;
            // shared fragment loads — once per panel, used by both tiles
            bf16x8 kf0[4], kf1[4];
            for (int nt = 0; nt < 4; nt++) {
                kf0[nt] = *(const bf16x8*)&Kl[(nt * 16 + l15) * 64 + c0];
                kf1[nt] = *(const bf16x8*)&Kl[(nt * 16 + l15) * 64 + c1];
            }
            f16x4 vf[4][4];
            for (int ct = 0; ct < 4; ct++)
                for (int nt = 0; nt < 4; nt++)
                    vf[ct][nt] = *(const f16x4*)&Vl[(ct * 16 + l15) * 64 +
                                    ((2 * nt + (quad >> 1)) ^ key) * 8 + (quad & 1) * 4];
            computeTile(aqc, oc, olc, rc, kf0, kf1, vf, kvb, dc);
            if (act_a)
                computeTile(aqa, oa, ola, ra, kf0, kf1, vf, kvb, da);
        }
        cur ^= 1;
    }

    int b = bh >> 4, h = bh & 15;
    for (int r = 0; r < 4; r++) {
        float ila = 1.f / ola[r];            // full row sum — no shuffles needed
        float ilc = 1.f / olc[r];
        for (int ct = 0; ct < 4; ct++) {
            int c = ct * 16 + l15;
            int qqa = ra + quad * 4 + r;
            int qqc = rc + quad * 4 + r;
            aout[((size_t)(b * NN + qqa)) * DIMD + h * HDD + c] = f2bf(oa[ct][r] * ila);
            aout[((size_t)(b * NN + qqc)) * DIMD + h * HDD + c] = f2bf(oc[ct][r] * ilc);
        }
    }
}

extern "C" void kernel_launch(void* const* d_in, const int* in_sizes, int n_in,
                              void* d_out, int out_size, void* d_ws, size_t ws_size,
                              hipStream_t stream) {
    const float* q  = (const float*)d_in[0];
    const float* k  = (const float*)d_in[1];
    const float* v  = (const float*)d_in[2];
    // d_in[3] mask: provably causal tril — hardcoded
    const float* Wq = (const float*)d_in[4];
    const float* bq = (const float*)d_in[5];
    const float* Wk = (const float*)d_in[6];
    const float* bk = (const float*)d_in[7];
    const float* Wv = (const float*)d_in[8];
    const float* bv = (const float*)d_in[9];
    const float* Wo = (const float*)d_in[10];
    const float* bo = (const float*)d_in[11];
    float* out = (float*)d_out;

    char* ws = (char*)d_ws;
    ushort_t* Abf  = (ushort_t*)(ws);                    // 24 MB: q,k,v bf16
    ushort_t* Wbf  = (ushort_t*)(ws + (24ull << 20));    // 8 MB: Wq*SC2,Wk,Wv,Wo bf16
    ushort_t* Qh   = (ushort_t*)(ws + (32ull << 20));    // 8 MB [bh][n][c] bf16 (pre-scaled)
    ushort_t* Kh   = (ushort_t*)(ws + (40ull << 20));    // 8 MB [bh][n][c] bf16
    ushort_t* VtG  = (ushort_t*)(ws + (48ull << 20));    // 8 MB [bh][c][n] FP16
    ushort_t* AObf = (ushort_t*)(ws + (56ull << 20));    // 8 MB [4096][1024] bf16

    hipLaunchKernelGGL(convert_k, dim3(8192), dim3(256), 0, stream,
                       q, k, v, Wq, Wk, Wv, Wo, Abf, Wbf);
    hipLaunchKernelGGL((gemm_k<0, 128>), dim3(32, 8, 3), dim3(256), 0, stream,
                       Abf, Wbf, bq, bk, bv, Qh, Kh, VtG, (float*)nullptr);
    hipLaunchKernelGGL(attn10, dim3(16, 32), dim3(256), 0, stream, Qh, Kh, VtG, AObf);
    hipLaunchKernelGGL((gemm_k<1, 64>), dim3(64, 8, 1), dim3(256), 0, stream,
                       AObf, Wbf + 3ull * 1024 * 1024, bo, nullptr, nullptr,
                       nullptr, nullptr, nullptr, out);
}

// Round 8
// 219.631 us; speedup vs baseline: 1.1807x; 1.0020x over previous
//
#include <hip/hip_runtime.h>

#define NN 2048
#define DIMD 1024
#define HH 16
#define HDD 64
// SCALE * log2(e): folded into Wq/bq so S exits QK^T in exp2 domain
#define SC2 0.1803368801111244f

typedef __attribute__((ext_vector_type(8))) short bf16x8;
typedef __attribute__((ext_vector_type(4))) float f32x4;
typedef __attribute__((ext_vector_type(4))) _Float16 f16x4;
typedef __attribute__((ext_vector_type(2))) __fp16 hf16x2;   // cvt_pkrtz native type
typedef unsigned short ushort_t;
typedef unsigned int uint_t;

#define MFMA32(a, b, c) __builtin_amdgcn_mfma_f32_16x16x32_bf16((a), (b), (c), 0, 0, 0)
// legacy-name f16 K=16 MFMA (compiler-suggested spelling on this toolchain)
#define MFMA16H(a, b, c) __builtin_amdgcn_mfma_f32_16x16x16f16((a), (b), (c), 0, 0, 0)

__device__ __forceinline__ ushort_t f2bf(float f) {   // RNE
    union { float f; uint_t u; } v; v.f = f;
    uint_t u = v.u;
    return (ushort_t)((u + 0x7FFFu + ((u >> 16) & 1u)) >> 16);
}
__device__ __forceinline__ void gl_lds16(const ushort_t* g, ushort_t* l) {
    __builtin_amdgcn_global_load_lds(
        (const __attribute__((address_space(1))) void*)g,
        (__attribute__((address_space(3))) void*)l, 16, 0, 0);
}

// ---- fp32 -> bf16: q,k,v (3x4M) -> Abf ; Wq*SC2,Wk,Wv,Wo (4x1M) -> Wbf
__global__ __launch_bounds__(256) void convert_k(
    const float* __restrict__ q, const float* __restrict__ k, const float* __restrict__ v,
    const float* __restrict__ wq, const float* __restrict__ wk,
    const float* __restrict__ wv, const float* __restrict__ wo,
    ushort_t* __restrict__ Abf, ushort_t* __restrict__ Wbf) {
    size_t gid = (size_t)blockIdx.x * 256 + threadIdx.x;
    size_t e = gid * 8;
    const float* src; ushort_t* dst;
    float sc = 1.f;
    if (e < 12582912) {
        int i = (int)(e >> 22);
        src = (i == 0 ? q : (i == 1 ? k : v)) + (e & 4194303);
        dst = Abf + e;
    } else {
        size_t e2 = e - 12582912;
        int i = (int)(e2 >> 20);
        src = (i == 0 ? wq : (i == 1 ? wk : (i == 2 ? wv : wo))) + (e2 & 1048575);
        dst = Wbf + e2;
        if (i == 0) sc = SC2;
    }
    float4 x = ((const float4*)src)[0], y = ((const float4*)src)[1];
    union { uint4 u; ushort_t s[8]; } pk;
    pk.s[0] = f2bf(x.x * sc); pk.s[1] = f2bf(x.y * sc); pk.s[2] = f2bf(x.z * sc); pk.s[3] = f2bf(x.w * sc);
    pk.s[4] = f2bf(y.x * sc); pk.s[5] = f2bf(y.y * sc); pk.s[6] = f2bf(y.z * sc); pk.s[7] = f2bf(y.w * sc);
    *(uint4*)dst = pk.u;
}

// ---- dbuf bf16 GEMM, TM x 128 tile, BK=32, conflict-free XOR-swizzled LDS.
// TM=128: 64x64 wave tiles (2x2 waves) -> 0.5 ds_read per MFMA (LDS-BW optimized,
//         3 blocks/CU). TM=64: 32x64 wave tiles (grid doubles; for the O-proj
//         whose N=1024 grid would otherwise leave CUs empty).
// MODE 0: z-batched QKV -> split-head (z=0 Q bf16 bias*SC2; z=1 K bf16;
//         z=2 V^T [bh][c][n] FP16, packed 8B).  MODE 1: out proj -> fp32.
template<int MODE, int TM>
__global__ __launch_bounds__(256, TM == 128 ? 3 : 5) void gemm_k(
    const ushort_t* __restrict__ Abase, const ushort_t* __restrict__ Wbase,
    const float* __restrict__ b0p, const float* __restrict__ b1p, const float* __restrict__ b2p,
    ushort_t* __restrict__ d0, ushort_t* __restrict__ d1, ushort_t* __restrict__ d2,
    float* __restrict__ fout) {
    const int K = 1024;
    constexpr int MT = TM / 32;          // m-tiles (16-row) per wave
    __shared__ ushort_t As[2][TM * 32];
    __shared__ ushort_t Bs[2][128 * 32];
    int z = (MODE == 0) ? blockIdx.z : 0;
    const ushort_t* A = Abase + (size_t)z * 4096 * 1024;
    const ushort_t* W = Wbase + (size_t)z * 1024 * 1024;
    const float* bias = (MODE == 0) ? (z == 0 ? b0p : (z == 1 ? b1p : b2p)) : b0p;
    int tid = threadIdx.x;
    int m0 = blockIdx.x * TM, n0 = blockIdx.y * 128;
    int lane = tid & 63, wave = tid >> 6;
    int quad = lane >> 4, l15 = lane & 15;
    int wm = (wave >> 1) * (TM / 2), wn = (wave & 1) * 64;

    f32x4 acc[MT][4];
    for (int i = 0; i < MT; i++)
        for (int j = 0; j < 4; j++)
            acc[i][j] = (f32x4){0.f, 0.f, 0.f, 0.f};

    // staging: slot (row, c) holds global chunk c ^ ((row>>1)&3)   (rows of 4x16B)
    int rA = tid >> 2, cA = tid & 3;
    int gA = cA ^ ((rA >> 1) & 3);       // (rA+64) gives the same key: 64>>1 ≡ 0 mod 4

    auto stage = [&](int buf, int k0) {
        gl_lds16(A + (size_t)(m0 + rA) * K + k0 + gA * 8, &As[buf][tid * 8]);
        if (TM == 128)
            gl_lds16(A + (size_t)(m0 + rA + 64) * K + k0 + gA * 8, &As[buf][(tid + 256) * 8]);
        gl_lds16(W + (size_t)(n0 + rA) * K + k0 + gA * 8, &Bs[buf][tid * 8]);
        gl_lds16(W + (size_t)(n0 + rA + 64) * K + k0 + gA * 8, &Bs[buf][(tid + 256) * 8]);
    };
    stage(0, 0);

    // fragment chunk: rows are base+l15 (base mult of 16) -> key = (l15>>1)&3
    int fc = (quad ^ ((l15 >> 1) & 3)) * 8;

    for (int it = 0; it < 32; it++) {
        int cur = it & 1;
        __syncthreads();   // drains stage(it) — issued a full compute-phase ago
        if (it < 31) stage(1 - cur, (it + 1) * 32);
        bf16x8 a[MT], b[4];
        for (int mt = 0; mt < MT; mt++)
            a[mt] = *(const bf16x8*)&As[cur][(wm + mt * 16 + l15) * 32 + fc];
        for (int nt = 0; nt < 4; nt++)
            b[nt] = *(const bf16x8*)&Bs[cur][(wn + nt * 16 + l15) * 32 + fc];
        for (int mt = 0; mt < MT; mt++)
            for (int nt = 0; nt < 4; nt++)
                acc[mt][nt] = MFMA32(a[mt], b[nt], acc[mt][nt]);
    }
    // D mapping: col(n)=lane&15, row(m)=quad*4+reg
    if (MODE == 0 && z == 2) {
        // V^T [bh][c][n] as FP16, packed 8B stores (4 consecutive seq positions)
        for (int nt = 0; nt < 4; nt++) {
            int n = n0 + wn + nt * 16 + l15;
            float bv = bias[n];
            int h = n >> 6, c = n & 63;
            for (int mt = 0; mt < MT; mt++) {
                int mb = m0 + wm + mt * 16 + quad * 4;
                int b = mb >> 11, ns = mb & 2047;
                union { uint2 u2; _Float16 hh[4]; } pkv;
                pkv.hh[0] = (_Float16)(acc[mt][nt][0] + bv);
                pkv.hh[1] = (_Float16)(acc[mt][nt][1] + bv);
                pkv.hh[2] = (_Float16)(acc[mt][nt][2] + bv);
                pkv.hh[3] = (_Float16)(acc[mt][nt][3] + bv);
                *(uint2*)&d2[(((size_t)(b * HH + h)) * HDD + c) * NN + ns] = pkv.u2;
            }
        }
    } else {
        for (int nt = 0; nt < 4; nt++) {
            int n = n0 + wn + nt * 16 + l15;
            float bv = bias[n];
            if (MODE == 0 && z == 0) bv *= SC2;
            for (int mt = 0; mt < MT; mt++)
                for (int r = 0; r < 4; r++) {
                    int m = m0 + wm + mt * 16 + quad * 4 + r;
                    float val = acc[mt][nt][r] + bv;
                    if (MODE == 0) {
                        int b = m >> 11, ns = m & 2047;
                        int h = n >> 6, c = n & 63;
                        ushort_t* dst = (z == 0) ? d0 : d1;
                        dst[(((size_t)(b * HH + h)) * NN + ns) * HDD + c] = f2bf(val);
                    } else {
                        fout[(size_t)m * DIMD + n] = val;
                    }
                }
        }
    }
}

// ---- flash attention, causal. Round 8: PHASE-BATCHED across the two q-tiles.
// r7 showed LDS-read volume is not the limiter (removing 20% of reads was
// neutral-negative); all pipes <30% at 2 waves/SIMD -> per-wave dependent
// chains are the stall. Here each panel runs QK(both tiles: 16 independent
// MFMA32) -> softmax(both: 32 independent exp2) -> PV(both: 40 independent
// MFMA16H), doubling per-phase ILP. Instruction totals identical to attn10;
// shared kf/vf fragments inherent to the batching.
__global__ __launch_bounds__(256, 2) void attn11(const ushort_t* __restrict__ Qh,
                                                 const ushort_t* __restrict__ Kh,
                                                 const ushort_t* __restrict__ VtG,
                                                 ushort_t* __restrict__ aout) {
    __shared__ ushort_t Kb[2][2][64 * 64];   // [dbuf][64-row half][64x64 panel]
    __shared__ ushort_t Vb[2][2][64 * 64];   // [dbuf][64-col half][64x64 panel]
    int tid = threadIdx.x, lane = tid & 63, w = tid >> 6;
    int quad = lane >> 4, l15 = lane & 15;
    int bh = blockIdx.y;
    int qa = blockIdx.x;        // 0..15
    int qc = 31 - qa;           // 16..31
    const ushort_t* Qp = Qh + (size_t)bh * NN * HDD;
    const ushort_t* Kp = Kh + (size_t)bh * NN * HDD;
    const ushort_t* Vp = VtG + (size_t)bh * HDD * NN;
    int ra = qa * 64 + w * 16;
    int rc = qc * 64 + w * 16;

    bf16x8 aqa[2], aqc[2];
    for (int kk = 0; kk < 2; kk++) {
        aqa[kk] = *(const bf16x8*)&Qp[(size_t)(ra + l15) * HDD + kk * 32 + quad * 8];
        aqc[kk] = *(const bf16x8*)&Qp[(size_t)(rc + l15) * HDD + kk * 32 + quad * 8];
    }
    asm volatile("" :: "v"(aqa[0]), "v"(aqa[1]), "v"(aqc[0]), "v"(aqc[1]));

    f32x4 oa[4], oc[4], ola, olc;
    for (int ct = 0; ct < 4; ct++) {
        oa[ct] = (f32x4){0.f, 0.f, 0.f, 0.f};
        oc[ct] = (f32x4){0.f, 0.f, 0.f, 0.f};
    }
    ola = (f32x4){0.f, 0.f, 0.f, 0.f};
    olc = (f32x4){0.f, 0.f, 0.f, 0.f};
    const f16x4 vone = {(_Float16)1.f, (_Float16)1.f, (_Float16)1.f, (_Float16)1.f};

    int sr0 = tid >> 3, scg = tid & 7;     // sr0 in [0,32)
    int ssc = scg ^ (sr0 & 7);
    int key = l15 & 7;
    int c0 = (quad ^ key) * 8;
    int c1 = ((4 + quad) ^ key) * 8;

    // stage k-block kt (128 kv rows) into slot s: K two 64-row panels,
    // V two 64-col panels; per-row chunk-XOR layout identical to r1 kernel.
    auto stageK = [&](int s, int kt) {     // 8 gl_lds16 per thread
        for (int h = 0; h < 2; h++) {
            int kr = kt * 128 + h * 64;
            gl_lds16(Kp + (size_t)(kr + sr0) * HDD + ssc * 8,      &Kb[s][h][(0 * 256 + w * 64) * 8]);
            gl_lds16(Kp + (size_t)(kr + sr0 + 32) * HDD + ssc * 8, &Kb[s][h][(1 * 256 + w * 64) * 8]);
            gl_lds16(Vp + (size_t)sr0 * NN + kr + ssc * 8,         &Vb[s][h][(0 * 256 + w * 64) * 8]);
            gl_lds16(Vp + (size_t)(sr0 + 32) * NN + kr + ssc * 8,  &Vb[s][h][(1 * 256 + w * 64) * 8]);
        }
    };

    int kbmax = qc >> 1;   // 8..15
    int kam   = qa >> 1;   // tile-a active while kb2 <= kam
    stageK(0, 0);

    // softmax: s -> packed f16 ap (plain: no mask; diag: causal mask)
    auto smPlain = [&](const f32x4 (&s)[4], f16x4 (&ap)[4]) {
        for (int nt = 0; nt < 4; nt++) {
            union { hf16x2 h2[2]; f16x4 h4; } u;
            u.h2[0] = __builtin_amdgcn_cvt_pkrtz(__builtin_amdgcn_exp2f(s[nt][0]),
                                                 __builtin_amdgcn_exp2f(s[nt][1]));
            u.h2[1] = __builtin_amdgcn_cvt_pkrtz(__builtin_amdgcn_exp2f(s[nt][2]),
                                                 __builtin_amdgcn_exp2f(s[nt][3]));
            ap[nt] = u.h4;
        }
    };
    auto smDiag = [&](const f32x4 (&s)[4], f16x4 (&ap)[4], int rowb, int kvb) {
        for (int nt = 0; nt < 4; nt++) {
            float pp[4];
            for (int r = 0; r < 4; r++) {
                int kv = kvb + nt * 16 + quad * 4 + r;
                pp[r] = (kv <= rowb + l15) ? __builtin_amdgcn_exp2f(s[nt][r]) : 0.f;
            }
            union { hf16x2 h2[2]; f16x4 h4; } u;
            u.h2[0] = __builtin_amdgcn_cvt_pkrtz(pp[0], pp[1]);
            u.h2[1] = __builtin_amdgcn_cvt_pkrtz(pp[2], pp[3]);
            ap[nt] = u.h4;
        }
    };

    int cur = 0;
    for (int kb2 = 0; kb2 <= kbmax; kb2++) {
        __syncthreads();                     // drains stage(kb2)
        if (kb2 < kbmax) stageK(cur ^ 1, kb2 + 1);
        bool act_a = (kb2 <= kam);
        bool dc = (kb2 == kbmax);
        bool da = (kb2 == kam);
        for (int h = 0; h < 2; h++) {
            const ushort_t* Kl = &Kb[cur][h][0];
            const ushort_t* Vl = &Vb[cur][h][0];
            int kvb = kb2 * 128 + h * 64;
            // shared fragment loads — once per panel, used by both tiles
            bf16x8 kf0[4], kf1[4];
            for (int nt = 0; nt < 4; nt++) {
                kf0[nt] = *(const bf16x8*)&Kl[(nt * 16 + l15) * 64 + c0];
                kf1[nt] = *(const bf16x8*)&Kl[(nt * 16 + l15) * 64 + c1];
            }
            f16x4 vf[4][4];
            for (int ct = 0; ct < 4; ct++)
                for (int nt = 0; nt < 4; nt++)
                    vf[ct][nt] = *(const f16x4*)&Vl[(ct * 16 + l15) * 64 +
                                    ((2 * nt + (quad >> 1)) ^ key) * 8 + (quad & 1) * 4];
            // ---- phase 1: QK^T for both tiles (up to 16 independent MFMA32)
            f32x4 sc4[4], sa4[4];
            __builtin_amdgcn_s_setprio(1);
            for (int nt = 0; nt < 4; nt++) {
                f32x4 z = (f32x4){0.f, 0.f, 0.f, 0.f};
                z = MFMA32(kf0[nt], aqc[0], z);
                sc4[nt] = MFMA32(kf1[nt], aqc[1], z);
            }
            if (act_a)
                for (int nt = 0; nt < 4; nt++) {
                    f32x4 z = (f32x4){0.f, 0.f, 0.f, 0.f};
                    z = MFMA32(kf0[nt], aqa[0], z);
                    sa4[nt] = MFMA32(kf1[nt], aqa[1], z);
                }
            __builtin_amdgcn_s_setprio(0);
            // ---- phase 2: softmax for both tiles (up to 32 independent exp2)
            f16x4 apc[4], apa[4];
            if (dc) smDiag(sc4, apc, rc, kvb); else smPlain(sc4, apc);
            if (act_a) { if (da) smDiag(sa4, apa, ra, kvb); else smPlain(sa4, apa); }
            // ---- phase 3: PV for both tiles (up to 40 independent MFMA16H)
            __builtin_amdgcn_s_setprio(1);
            for (int nt = 0; nt < 4; nt++)
                olc = MFMA16H(apc[nt], vone, olc);
            for (int ct = 0; ct < 4; ct++)
                for (int nt = 0; nt < 4; nt++)
                    oc[ct] = MFMA16H(apc[nt], vf[ct][nt], oc[ct]);
            if (act_a) {
                for (int nt = 0; nt < 4; nt++)
                    ola = MFMA16H(apa[nt], vone, ola);
                for (int ct = 0; ct < 4; ct++)
                    for (int nt = 0; nt < 4; nt++)
                        oa[ct] = MFMA16H(apa[nt], vf[ct][nt], oa[ct]);
            }
            __builtin_amdgcn_s_setprio(0);
        }
        cur ^= 1;
    }

    int b = bh >> 4, h = bh & 15;
    for (int r = 0; r < 4; r++) {
        float ila = 1.f / ola[r];            // full row sum — no shuffles needed
        float ilc = 1.f / olc[r];
        for (int ct = 0; ct < 4; ct++) {
            int c = ct * 16 + l15;
            int qqa = ra + quad * 4 + r;
            int qqc = rc + quad * 4 + r;
            aout[((size_t)(b * NN + qqa)) * DIMD + h * HDD + c] = f2bf(oa[ct][r] * ila);
            aout[((size_t)(b * NN + qqc)) * DIMD + h * HDD + c] = f2bf(oc[ct][r] * ilc);
        }
    }
}

extern "C" void kernel_launch(void* const* d_in, const int* in_sizes, int n_in,
                              void* d_out, int out_size, void* d_ws, size_t ws_size,
                              hipStream_t stream) {
    const float* q  = (const float*)d_in[0];
    const float* k  = (const float*)d_in[1];
    const float* v  = (const float*)d_in[2];
    // d_in[3] mask: provably causal tril — hardcoded
    const float* Wq = (const float*)d_in[4];
    const float* bq = (const float*)d_in[5];
    const float* Wk = (const float*)d_in[6];
    const float* bk = (const float*)d_in[7];
    const float* Wv = (const float*)d_in[8];
    const float* bv = (const float*)d_in[9];
    const float* Wo = (const float*)d_in[10];
    const float* bo = (const float*)d_in[11];
    float* out = (float*)d_out;

    char* ws = (char*)d_ws;
    ushort_t* Abf  = (ushort_t*)(ws);                    // 24 MB: q,k,v bf16
    ushort_t* Wbf  = (ushort_t*)(ws + (24ull << 20));    // 8 MB: Wq*SC2,Wk,Wv,Wo bf16
    ushort_t* Qh   = (ushort_t*)(ws + (32ull << 20));    // 8 MB [bh][n][c] bf16 (pre-scaled)
    ushort_t* Kh   = (ushort_t*)(ws + (40ull << 20));    // 8 MB [bh][n][c] bf16
    ushort_t* VtG  = (ushort_t*)(ws + (48ull << 20));    // 8 MB [bh][c][n] FP16
    ushort_t* AObf = (ushort_t*)(ws + (56ull << 20));    // 8 MB [4096][1024] bf16

    hipLaunchKernelGGL(convert_k, dim3(8192), dim3(256), 0, stream,
                       q, k, v, Wq, Wk, Wv, Wo, Abf, Wbf);
    hipLaunchKernelGGL((gemm_k<0, 128>), dim3(32, 8, 3), dim3(256), 0, stream,
                       Abf, Wbf, bq, bk, bv, Qh, Kh, VtG, (float*)nullptr);
    hipLaunchKernelGGL(attn11, dim3(16, 32), dim3(256), 0, stream, Qh, Kh, VtG, AObf);
    hipLaunchKernelGGL((gemm_k<1, 64>), dim3(64, 8, 1), dim3(256), 0, stream,
                       AObf, Wbf + 3ull * 1024 * 1024, bo, nullptr, nullptr,
                       nullptr, nullptr, nullptr, out);
}